// Round 2
// baseline (205.850 us; speedup 1.0000x reference)
//
#include <hip/hip_runtime.h>

// LIF constants (match reference)
constexpr int   SEQ      = 100;
constexpr float DT_TAUI  = 0.1f;   // DT * TAU_MEM_INV
constexpr float V_TH     = 1.0f;

// clang native vector type — required by __builtin_nontemporal_store
typedef float f32x4 __attribute__((ext_vector_type(4)));

// One thread per 4 neurons. v, I in registers; 100 coalesced 16B
// streaming stores per thread (output written once, >L2 -> nontemporal).
__global__ __launch_bounds__(256) void lif_encode_kernel(
    const float* __restrict__ in, float* __restrict__ out, int n4)
{
    int i = blockIdx.x * blockDim.x + threadIdx.x;
    if (i >= n4) return;

    const f32x4* in4  = reinterpret_cast<const f32x4*>(in);
    f32x4*       out4 = reinterpret_cast<f32x4*>(out);

    f32x4 I = in4[i];
    f32x4 v = {0.f, 0.f, 0.f, 0.f};

    for (int t = 0; t < SEQ; ++t) {
        // v' = v + 0.1*(I - v)
        v.x += DT_TAUI * (I.x - v.x);
        v.y += DT_TAUI * (I.y - v.y);
        v.z += DT_TAUI * (I.z - v.z);
        v.w += DT_TAUI * (I.w - v.w);
        // z = H(v' - v_th); v'' = v' - z*(v' - v_reset), v_reset = 0
        f32x4 z;
        z.x = (v.x > V_TH) ? 1.f : 0.f;
        z.y = (v.y > V_TH) ? 1.f : 0.f;
        z.z = (v.z > V_TH) ? 1.f : 0.f;
        z.w = (v.w > V_TH) ? 1.f : 0.f;
        v.x -= z.x * v.x;
        v.y -= z.y * v.y;
        v.z -= z.z * v.z;
        v.w -= z.w * v.w;
        __builtin_nontemporal_store(z, &out4[(size_t)t * n4 + i]);
    }
}

extern "C" void kernel_launch(void* const* d_in, const int* in_sizes, int n_in,
                              void* d_out, int out_size, void* d_ws, size_t ws_size,
                              hipStream_t stream)
{
    const float* in  = reinterpret_cast<const float*>(d_in[0]);
    float*       out = reinterpret_cast<float*>(d_out);
    int n  = in_sizes[0];      // 64*8192 = 524288 (divisible by 4)
    int n4 = n / 4;
    int block = 256;
    int grid  = (n4 + block - 1) / block;   // 512
    lif_encode_kernel<<<grid, block, 0, stream>>>(in, out, n4);
}

// Round 3
// 195.938 us; speedup vs baseline: 1.0506x; 1.0506x over previous
//
#include <hip/hip_runtime.h>

// LIF constants (match reference)
constexpr int   SEQ      = 100;
constexpr float DT_TAUI  = 0.1f;   // DT * TAU_MEM_INV
constexpr float V_TH     = 1.0f;

typedef float f32x2 __attribute__((ext_vector_type(2)));

// One thread per 2 neurons. v, I in registers; 100 coalesced 8B plain
// (cached) stores per thread — L2 absorbs the 2 MB/step write tile and
// drains to HBM asynchronously. 1024 blocks -> 16 waves/CU for store MLP.
__global__ __launch_bounds__(256) void lif_encode_kernel(
    const float* __restrict__ in, float* __restrict__ out, int n2)
{
    int i = blockIdx.x * blockDim.x + threadIdx.x;
    if (i >= n2) return;

    const f32x2* in2  = reinterpret_cast<const f32x2*>(in);
    f32x2*       out2 = reinterpret_cast<f32x2*>(out);

    f32x2 I = in2[i];
    f32x2 v = {0.f, 0.f};

    for (int t = 0; t < SEQ; ++t) {
        // v' = v + 0.1*(I - v)
        v.x += DT_TAUI * (I.x - v.x);
        v.y += DT_TAUI * (I.y - v.y);
        // z = H(v' - v_th); v'' = v' - z*(v' - v_reset), v_reset = 0
        f32x2 z;
        z.x = (v.x > V_TH) ? 1.f : 0.f;
        z.y = (v.y > V_TH) ? 1.f : 0.f;
        v.x -= z.x * v.x;
        v.y -= z.y * v.y;
        out2[(size_t)t * n2 + i] = z;
    }
}

extern "C" void kernel_launch(void* const* d_in, const int* in_sizes, int n_in,
                              void* d_out, int out_size, void* d_ws, size_t ws_size,
                              hipStream_t stream)
{
    const float* in  = reinterpret_cast<const float*>(d_in[0]);
    float*       out = reinterpret_cast<float*>(d_out);
    int n  = in_sizes[0];      // 64*8192 = 524288
    int n2 = n / 2;            // 262144 threads
    int block = 256;
    int grid  = (n2 + block - 1) / block;   // 1024
    lif_encode_kernel<<<grid, block, 0, stream>>>(in, out, n2);
}